// Round 1
// baseline (17914.415 us; speedup 1.0000x reference)
//
#include <hip/hip_runtime.h>

// LSTM_13159779795583 : 2-layer LSTM (B=32,T=512,IN=256,H=1024) + FC(1024->256)
//
// Design (round 1, correctness-first but structurally fast):
//  - persistent cooperative kernel, 128 WGs x 512 thr (8 waves, <=256 VGPR/wave)
//  - each WG owns 8 hidden units per layer (32 gate rows); weight fragments for
//    W_hh0/W_ih0/W_ih1/W_hh1 live in VGPRs (loaded+packed once, fp16)
//  - layers software-pipelined: 513 grid-barrier steps instead of 1024
//  - h0/h1 histories are write-once fp16 slot arrays in d_ws (no WAR hazards,
//    no stale-cache reads; h1 history doubles as FC input)
//  - per step: A-frags (h / x) loaded straight from global in MFMA layout,
//    v_mfma_f32_32x32x16_f16, partials -> LDS -> elementwise cell -> barrier
//  - grid barrier: per-thread __threadfence + leader agent-scope atomic+spin
//  - epilogue FC = separate MFMA kernel; x and fc_w pre-cast to fp16

#define T_STEPS 512
#define BATCH   32
#define IN_DIM  256
#define HID     1024
#define OUT_DIM 256
#define NWG     128
#define TPB     512
#define UNITS   8     // hidden units per WG per layer
#define ROWS    32    // 4 gates * UNITS

typedef _Float16 half8  __attribute__((ext_vector_type(8)));
typedef float    f32x16 __attribute__((ext_vector_type(16)));

__device__ __forceinline__ float sigm(float x)      { return 1.f / (1.f + __expf(-x)); }
__device__ __forceinline__ float tanh_fast(float x) { return 2.f / (1.f + __expf(-2.f * x)) - 1.f; }

__global__ __launch_bounds__(TPB, 2) void lstm_persist(
    const float* __restrict__ W_ih0, const float* __restrict__ W_hh0,
    const float* __restrict__ b_ih0, const float* __restrict__ b_hh0,
    const float* __restrict__ W_ih1, const float* __restrict__ W_hh1,
    const float* __restrict__ b_ih1, const float* __restrict__ b_hh1,
    const _Float16* __restrict__ xb,
    _Float16* __restrict__ h0a, _Float16* __restrict__ h1a,
    unsigned* __restrict__ barcnt, unsigned* __restrict__ bargen)
{
    __shared__ float stage[8][BATCH][ROWS];   // per-wave partial gates
    __shared__ float cst[2][BATCH][UNITS];    // cell state, both layers
    __shared__ float biasS[2][ROWS];          // b_ih + b_hh, this WG's rows

    const int tid  = threadIdx.x;
    const int w    = tid >> 6;        // wave id 0..7
    const int lane = tid & 63;
    const int rho  = lane & 31;       // MFMA n-row / A m-row
    const int kg   = (lane >> 5) << 3;// k sub-offset (0 or 8)
    const int blk  = blockIdx.x;

    // wave roles: matrix 0=W_hh0 1=W_ih0 2=W_ih1 3=W_hh1 ; K-range split
    const int matv[8]   = {0, 0,   1, 2, 2,   3, 3,   1};
    const int kbasev[8] = {0, 512, 0, 0, 512, 0, 512, 128};
    const int nkv[8]    = {32, 32, 8, 32, 32, 32, 32, 8};
    const int mat   = matv[w];
    const int kbase = kbasev[w];
    const int nk    = nkv[w];
    const int layer = (mat >= 2) ? 1 : 0;

    const float* wptr; int rowlen;
    if      (mat == 0) { wptr = W_hh0; rowlen = HID;    }
    else if (mat == 1) { wptr = W_ih0; rowlen = IN_DIM; }
    else if (mat == 2) { wptr = W_ih1; rowlen = HID;    }
    else               { wptr = W_hh1; rowlen = HID;    }

    // this lane's weight row: gate = rho>>3, unit = blk*8 + (rho&7)
    const int grow = (rho >> 3) * HID + blk * UNITS + (rho & 7);

    // ---- load + pack B fragments into registers (fp32 -> fp16), once ----
    half8 B[32];
    #pragma unroll
    for (int kk = 0; kk < 32; ++kk) {
        half8 bf;
        if (kk < nk) {
            const float* p = wptr + (size_t)grow * rowlen + kbase + kk * 16 + kg;
            float4 lo = *(const float4*)p;
            float4 hi = *(const float4*)(p + 4);
            bf[0] = (_Float16)lo.x; bf[1] = (_Float16)lo.y;
            bf[2] = (_Float16)lo.z; bf[3] = (_Float16)lo.w;
            bf[4] = (_Float16)hi.x; bf[5] = (_Float16)hi.y;
            bf[6] = (_Float16)hi.z; bf[7] = (_Float16)hi.w;
        } else {
            #pragma unroll
            for (int j = 0; j < 8; ++j) bf[j] = (_Float16)0.f;
        }
        B[kk] = bf;
    }

    // ---- init: biases, cell state, zero h slot 0 of both layers ----
    if (tid < ROWS) {
        int gr = (tid >> 3) * HID + blk * UNITS + (tid & 7);
        biasS[0][tid] = b_ih0[gr] + b_hh0[gr];
        biasS[1][tid] = b_ih1[gr] + b_hh1[gr];
    }
    ((float*)cst)[tid] = 0.f;  // 2*32*8 = 512 floats, one per thread
    for (int i = blk * TPB + tid; i < BATCH * HID; i += NWG * TPB) {
        h0a[i] = (_Float16)0.f;
        h1a[i] = (_Float16)0.f;
    }

    unsigned phase = 0;
    auto gbar = [&]() {
        __threadfence();        // push this thread's stores toward L3
        __syncthreads();
        ++phase;
        if (tid == 0) {
            unsigned a = __hip_atomic_fetch_add(barcnt, 1u, __ATOMIC_ACQ_REL,
                                                __HIP_MEMORY_SCOPE_AGENT);
            if (a == NWG - 1) {
                __hip_atomic_store(barcnt, 0u, __ATOMIC_RELAXED, __HIP_MEMORY_SCOPE_AGENT);
                __hip_atomic_store(bargen, phase, __ATOMIC_RELEASE, __HIP_MEMORY_SCOPE_AGENT);
            } else {
                while (__hip_atomic_load(bargen, __ATOMIC_ACQUIRE,
                                         __HIP_MEMORY_SCOPE_AGENT) < phase)
                    __builtin_amdgcn_s_sleep(2);
            }
        }
        __syncthreads();
    };

    gbar();  // h slot-0 zeros visible everywhere before step 0

    // ---- pipelined main loop: step s does layer0@t=s and layer1@t=s-1 ----
    for (int s = 0; s <= T_STEPS; ++s) {
        const bool act = (layer == 0) ? (s < T_STEPS) : (s >= 1);
        if (act) {
            const _Float16* ab; int akdim;
            if      (mat == 1) { ab = xb  + (size_t)s * BATCH * IN_DIM;      akdim = IN_DIM; }
            else if (mat == 3) { ab = h1a + (size_t)(s - 1) * BATCH * HID;   akdim = HID;    }
            else               { ab = h0a + (size_t)s * BATCH * HID;         akdim = HID;    }
            const _Float16* ap = ab + (size_t)rho * akdim + kbase + kg;

            f32x16 acc0, acc1;
            #pragma unroll
            for (int r = 0; r < 16; ++r) { acc0[r] = 0.f; acc1[r] = 0.f; }

            #pragma unroll
            for (int kk = 0; kk < 32; kk += 2) {
                if (kk < nk) {
                    half8 a = *(const half8*)(ap + kk * 16);
                    acc0 = __builtin_amdgcn_mfma_f32_32x32x16_f16(a, B[kk], acc0, 0, 0, 0);
                }
                if (kk + 1 < nk) {
                    half8 a = *(const half8*)(ap + (kk + 1) * 16);
                    acc1 = __builtin_amdgcn_mfma_f32_32x32x16_f16(a, B[kk + 1], acc1, 0, 0, 0);
                }
            }
            // C/D layout (verified m74/m101): n = lane&31, m = (r&3)+8*(r>>2)+4*(lane>>5)
            #pragma unroll
            for (int r = 0; r < 16; ++r) {
                int m = (r & 3) + ((r >> 2) << 3) + ((lane >> 5) << 2);
                stage[w][m][rho] = acc0[r] + acc1[r];
            }
        }
        __syncthreads();

        // ---- elementwise LSTM cell: 2 layers * 32 batch * 8 units = 512 thr ----
        {
            const int L = tid >> 8;
            const int b = (tid >> 3) & 31;
            const int u = tid & 7;
            const bool eact = (L == 0) ? (s < T_STEPS) : (s >= 1);
            if (eact) {
                float pre[4];
                #pragma unroll
                for (int g = 0; g < 4; ++g) {
                    int n = g * 8 + u;
                    float v = biasS[L][n];
                    if (L == 0) v += stage[0][b][n] + stage[1][b][n] + stage[2][b][n] + stage[7][b][n];
                    else        v += stage[3][b][n] + stage[4][b][n] + stage[5][b][n] + stage[6][b][n];
                    pre[g] = v;
                }
                float iv = sigm(pre[0]);
                float fv = sigm(pre[1]);
                float gv = tanh_fast(pre[2]);
                float ov = sigm(pre[3]);
                float c  = fv * cst[L][b][u] + iv * gv;
                cst[L][b][u] = c;
                float h  = ov * tanh_fast(c);
                size_t off = (size_t)b * HID + (size_t)blk * UNITS + u;
                if (L == 0) h0a[(size_t)(s + 1) * BATCH * HID + off] = (_Float16)h;
                else        h1a[(size_t)s       * BATCH * HID + off] = (_Float16)h;
            }
        }
        gbar();
    }
}

// ---- epilogue FC: out[b][t][o] = sum_h h1[t][b][h]*fc_w[o][h] + fc_b[o] ----
__global__ __launch_bounds__(256) void fc_kern(
    const _Float16* __restrict__ h1a, const _Float16* __restrict__ fcwb,
    const float* __restrict__ fc_b, float* __restrict__ out)
{
    const int wv   = threadIdx.x >> 6;
    const int lane = threadIdx.x & 63;
    const int t    = blockIdx.x * 4 + wv;   // grid 128 -> t = 0..511
    const int kg   = (lane >> 5) << 3;
    const _Float16* ab = h1a + ((size_t)(t + 1) * BATCH + (lane & 31)) * HID + kg;

    #pragma unroll 1
    for (int nt = 0; nt < 8; ++nt) {
        const _Float16* bb = fcwb + (size_t)(nt * 32 + (lane & 31)) * HID + kg;
        f32x16 acc0, acc1;
        #pragma unroll
        for (int r = 0; r < 16; ++r) { acc0[r] = 0.f; acc1[r] = 0.f; }
        #pragma unroll
        for (int kk = 0; kk < 64; kk += 2) {
            half8 a0 = *(const half8*)(ab + kk * 16);
            half8 b0 = *(const half8*)(bb + kk * 16);
            acc0 = __builtin_amdgcn_mfma_f32_32x32x16_f16(a0, b0, acc0, 0, 0, 0);
            half8 a1 = *(const half8*)(ab + (kk + 1) * 16);
            half8 b1 = *(const half8*)(bb + (kk + 1) * 16);
            acc1 = __builtin_amdgcn_mfma_f32_32x32x16_f16(a1, b1, acc1, 0, 0, 0);
        }
        const int o = nt * 32 + (lane & 31);
        const float bias = fc_b[o];
        #pragma unroll
        for (int r = 0; r < 16; ++r) {
            int m = (r & 3) + ((r >> 2) << 3) + ((lane >> 5) << 2);  // batch b
            out[(size_t)m * (T_STEPS * OUT_DIM) + (size_t)t * OUT_DIM + o]
                = acc0[r] + acc1[r] + bias;
        }
    }
}

// ---- pre-cast x (-> [t][b][d] fp16) and fc_w (-> fp16) ----
__global__ __launch_bounds__(256) void precast(
    const float* __restrict__ x, const float* __restrict__ fcw,
    _Float16* __restrict__ xb, _Float16* __restrict__ fcwb)
{
    const int idx = blockIdx.x * 256 + threadIdx.x;
    const int N1 = T_STEPS * BATCH * IN_DIM / 4;  // 1048576
    const int N2 = OUT_DIM * HID / 4;             // 65536
    if (idx < N1) {
        int e = idx << 2;
        int d = e & (IN_DIM - 1);
        int bt = e >> 8;
        int b = bt & 31;
        int t = bt >> 5;
        float4 v = *(const float4*)(x + ((size_t)b * T_STEPS + t) * IN_DIM + d);
        _Float16* dst = xb + e;
        dst[0] = (_Float16)v.x; dst[1] = (_Float16)v.y;
        dst[2] = (_Float16)v.z; dst[3] = (_Float16)v.w;
    } else if (idx < N1 + N2) {
        int e = (idx - N1) << 2;
        float4 v = *(const float4*)(fcw + e);
        _Float16* dst = fcwb + e;
        dst[0] = (_Float16)v.x; dst[1] = (_Float16)v.y;
        dst[2] = (_Float16)v.z; dst[3] = (_Float16)v.w;
    }
}

extern "C" void kernel_launch(void* const* d_in, const int* in_sizes, int n_in,
                              void* d_out, int out_size, void* d_ws, size_t ws_size,
                              hipStream_t stream) {
    const float* x     = (const float*)d_in[0];
    const float* W_ih0 = (const float*)d_in[1];
    const float* W_hh0 = (const float*)d_in[2];
    const float* b_ih0 = (const float*)d_in[3];
    const float* b_hh0 = (const float*)d_in[4];
    const float* W_ih1 = (const float*)d_in[5];
    const float* W_hh1 = (const float*)d_in[6];
    const float* b_ih1 = (const float*)d_in[7];
    const float* b_hh1 = (const float*)d_in[8];
    const float* fc_w  = (const float*)d_in[9];
    const float* fc_b  = (const float*)d_in[10];
    float* out = (float*)d_out;

    char* ws = (char*)d_ws;
    unsigned* barcnt = (unsigned*)ws;           // cacheline 0
    unsigned* bargen = (unsigned*)(ws + 128);   // cacheline 1
    size_t off = 256;
    _Float16* xb   = (_Float16*)(ws + off); off += (size_t)T_STEPS * BATCH * IN_DIM * 2;
    _Float16* h0a  = (_Float16*)(ws + off); off += (size_t)(T_STEPS + 1) * BATCH * HID * 2;
    _Float16* h1a  = (_Float16*)(ws + off); off += (size_t)(T_STEPS + 1) * BATCH * HID * 2;
    _Float16* fcwb = (_Float16*)(ws + off); off += (size_t)OUT_DIM * HID * 2;
    // total ws use ~73 MB

    hipMemsetAsync(ws, 0, 256, stream);  // zero barrier state every launch
    precast<<<4352, 256, 0, stream>>>(x, fc_w, xb, fcwb);
    lstm_persist<<<NWG, TPB, 0, stream>>>(W_ih0, W_hh0, b_ih0, b_hh0,
                                          W_ih1, W_hh1, b_ih1, b_hh1,
                                          xb, h0a, h1a, barcnt, bargen);
    fc_kern<<<128, 256, 0, stream>>>(h1a, fcwb, fc_b, out);
}

// Round 2
// 5292.953 us; speedup vs baseline: 3.3846x; 3.3846x over previous
//
#include <hip/hip_runtime.h>
#include <string.h>

// LSTM_13159779795583 : 2-layer LSTM (B=32,T=512,IN=256,H=1024) + FC(1024->256)
//
// Round 2: fence-free distributed grid barrier.
//  - ALL global stores in the persistent kernel are RELAXED agent-scope atomic
//    stores (write-through to coherence point; L2 never holds dirty shared
//    data) -> no buffer_wbl2 / buffer_inv anywhere in the steady state.
//  - barrier: per-WG flag line (128B apart) + WG0/wave0 aggregation + gen
//    broadcast replicated x8 lines; all polls RELAXED (no L2 invalidates).
//  - cell phase: 256 threads x 2 units -> h stored as packed 2xfp16 u32.
//  - stage LDS padded [32][33] to kill 8-way bank conflicts.
//  - everything else (wave roles, MFMA layout, pipelined layers) as round 1.

#define T_STEPS 512
#define BATCH   32
#define IN_DIM  256
#define HID     1024
#define OUT_DIM 256
#define NWG     128
#define TPB     512
#define UNITS   8     // hidden units per WG per layer
#define ROWS    32    // 4 gates * UNITS

typedef _Float16 half8  __attribute__((ext_vector_type(8)));
typedef float    f32x16 __attribute__((ext_vector_type(16)));

__device__ __forceinline__ float sigm(float x)      { return 1.f / (1.f + __expf(-x)); }
__device__ __forceinline__ float tanh_fast(float x) { return 2.f / (1.f + __expf(-2.f * x)) - 1.f; }

#define ATOMIC_ST(p, v) __hip_atomic_store((p), (v), __ATOMIC_RELAXED, __HIP_MEMORY_SCOPE_AGENT)
#define ATOMIC_LD(p)    __hip_atomic_load((p), __ATOMIC_RELAXED, __HIP_MEMORY_SCOPE_AGENT)

__global__ __launch_bounds__(TPB, 2) void lstm_persist(
    const float* __restrict__ W_ih0, const float* __restrict__ W_hh0,
    const float* __restrict__ b_ih0, const float* __restrict__ b_hh0,
    const float* __restrict__ W_ih1, const float* __restrict__ W_hh1,
    const float* __restrict__ b_ih1, const float* __restrict__ b_hh1,
    const _Float16* __restrict__ xb,
    _Float16* __restrict__ h0a, _Float16* __restrict__ h1a,
    unsigned* __restrict__ flags, unsigned* __restrict__ gen)
{
    __shared__ float stage[8][BATCH][33];     // padded: kills 8-way conflicts
    __shared__ float cst[2][BATCH][UNITS];    // cell state, both layers
    __shared__ float biasS[2][ROWS];          // b_ih + b_hh, this WG's rows

    const int tid  = threadIdx.x;
    const int w    = tid >> 6;        // wave id 0..7
    const int lane = tid & 63;
    const int rho  = lane & 31;       // MFMA n-row / A m-row
    const int kg   = (lane >> 5) << 3;// k sub-offset (0 or 8)
    const int blk  = blockIdx.x;

    // wave roles: matrix 0=W_hh0 1=W_ih0 2=W_ih1 3=W_hh1 ; K-range split
    const int matv[8]   = {0, 0,   1, 2, 2,   3, 3,   1};
    const int kbasev[8] = {0, 512, 0, 0, 512, 0, 512, 128};
    const int nkv[8]    = {32, 32, 8, 32, 32, 32, 32, 8};
    const int mat   = matv[w];
    const int kbase = kbasev[w];
    const int nk    = nkv[w];
    const int layer = (mat >= 2) ? 1 : 0;

    const float* wptr; int rowlen;
    if      (mat == 0) { wptr = W_hh0; rowlen = HID;    }
    else if (mat == 1) { wptr = W_ih0; rowlen = IN_DIM; }
    else if (mat == 2) { wptr = W_ih1; rowlen = HID;    }
    else               { wptr = W_hh1; rowlen = HID;    }

    // this lane's weight row: gate = rho>>3, unit = blk*8 + (rho&7)
    const int grow = (rho >> 3) * HID + blk * UNITS + (rho & 7);

    // ---- load + pack B fragments into registers (fp32 -> fp16), once ----
    half8 B[32];
    #pragma unroll
    for (int kk = 0; kk < 32; ++kk) {
        half8 bf;
        if (kk < nk) {
            const float* p = wptr + (size_t)grow * rowlen + kbase + kk * 16 + kg;
            float4 lo = *(const float4*)p;
            float4 hi = *(const float4*)(p + 4);
            bf[0] = (_Float16)lo.x; bf[1] = (_Float16)lo.y;
            bf[2] = (_Float16)lo.z; bf[3] = (_Float16)lo.w;
            bf[4] = (_Float16)hi.x; bf[5] = (_Float16)hi.y;
            bf[6] = (_Float16)hi.z; bf[7] = (_Float16)hi.w;
        } else {
            #pragma unroll
            for (int j = 0; j < 8; ++j) bf[j] = (_Float16)0.f;
        }
        B[kk] = bf;
    }

    // ---- init: biases, cell state, zero h slot 0 (atomic WT stores) ----
    if (tid < ROWS) {
        int gr = (tid >> 3) * HID + blk * UNITS + (tid & 7);
        biasS[0][tid] = b_ih0[gr] + b_hh0[gr];
        biasS[1][tid] = b_ih1[gr] + b_hh1[gr];
    }
    ((float*)cst)[tid] = 0.f;  // 2*32*8 = 512 floats, one per thread
    {
        int i = blk * TPB + tid;
        if (i < BATCH * HID / 2) {
            ATOMIC_ST((unsigned*)h0a + i, 0u);
            ATOMIC_ST((unsigned*)h1a + i, 0u);
        }
    }

    unsigned phase = 0;
    auto gbar = [&]() {
        __syncthreads();   // vmcnt(0) drain: WG's WT stores globally visible
        ++phase;
        if (tid == 0)
            ATOMIC_ST(&flags[blk * 32], phase);
        if (blk == 0 && w == 0) {
            // master: 64 lanes poll 2 flags each (128B-strided lines)
            const int i0 = lane * 2, i1 = lane * 2 + 1;
            bool d0 = false, d1 = false;
            for (;;) {
                if (!d0) d0 = ATOMIC_LD(&flags[i0 * 32]) >= phase;
                if (!d1) d1 = ATOMIC_LD(&flags[i1 * 32]) >= phase;
                if (__all(d0 && d1)) break;
            }
            if (lane < 8)
                ATOMIC_ST(&gen[lane * 32], phase);   // 8 replicated lines
        }
        if (tid == 0) {
            while (ATOMIC_LD(&gen[(blk & 7) * 32]) < phase) {}
        }
        __syncthreads();
    };

    gbar();  // h slot-0 zeros visible everywhere before step 0

    // ---- pipelined main loop: step s does layer0@t=s and layer1@t=s-1 ----
    for (int s = 0; s <= T_STEPS; ++s) {
        const bool act = (layer == 0) ? (s < T_STEPS) : (s >= 1);
        if (act) {
            const _Float16* ab; int akdim;
            if      (mat == 1) { ab = xb  + (size_t)s * BATCH * IN_DIM;      akdim = IN_DIM; }
            else if (mat == 3) { ab = h1a + (size_t)(s - 1) * BATCH * HID;   akdim = HID;    }
            else               { ab = h0a + (size_t)s * BATCH * HID;         akdim = HID;    }
            const _Float16* ap = ab + (size_t)rho * akdim + kbase + kg;

            f32x16 acc0, acc1;
            #pragma unroll
            for (int r = 0; r < 16; ++r) { acc0[r] = 0.f; acc1[r] = 0.f; }

            #pragma unroll
            for (int kk = 0; kk < 32; kk += 2) {
                if (kk < nk) {
                    half8 a = *(const half8*)(ap + kk * 16);
                    acc0 = __builtin_amdgcn_mfma_f32_32x32x16_f16(a, B[kk], acc0, 0, 0, 0);
                }
                if (kk + 1 < nk) {
                    half8 a = *(const half8*)(ap + (kk + 1) * 16);
                    acc1 = __builtin_amdgcn_mfma_f32_32x32x16_f16(a, B[kk + 1], acc1, 0, 0, 0);
                }
            }
            // C/D layout: n = lane&31, m = (r&3)+8*(r>>2)+4*(lane>>5)
            #pragma unroll
            for (int r = 0; r < 16; ++r) {
                int m = (r & 3) + ((r >> 2) << 3) + ((lane >> 5) << 2);
                stage[w][m][rho] = acc0[r] + acc1[r];
            }
        }
        __syncthreads();

        // ---- cell: 256 threads, each 2 layers-worth? no: (L,b,u-pair) ----
        if (tid < 256) {
            const int L  = tid >> 7;
            const int r7 = tid & 127;
            const int b  = r7 >> 2;
            const int u0 = (r7 & 3) * 2;
            const bool eact = (L == 0) ? (s < T_STEPS) : (s >= 1);
            if (eact) {
                float hv[2];
                #pragma unroll
                for (int j = 0; j < 2; ++j) {
                    const int u = u0 + j;
                    float pre[4];
                    #pragma unroll
                    for (int g = 0; g < 4; ++g) {
                        int n = g * 8 + u;
                        float v = biasS[L][n];
                        if (L == 0) v += stage[0][b][n] + stage[1][b][n] + stage[2][b][n] + stage[7][b][n];
                        else        v += stage[3][b][n] + stage[4][b][n] + stage[5][b][n] + stage[6][b][n];
                        pre[g] = v;
                    }
                    float iv = sigm(pre[0]);
                    float fv = sigm(pre[1]);
                    float gv = tanh_fast(pre[2]);
                    float ov = sigm(pre[3]);
                    float c  = fv * cst[L][b][u] + iv * gv;
                    cst[L][b][u] = c;
                    hv[j] = ov * tanh_fast(c);
                }
                _Float16 h2[2] = { (_Float16)hv[0], (_Float16)hv[1] };
                unsigned pk;
                memcpy(&pk, h2, 4);
                size_t off32 = ((size_t)b * HID + blk * UNITS + u0) >> 1;
                if (L == 0)
                    ATOMIC_ST((unsigned*)h0a + ((size_t)(s + 1) * BATCH * HID >> 1) + off32, pk);
                else
                    ATOMIC_ST((unsigned*)h1a + ((size_t)s * BATCH * HID >> 1) + off32, pk);
            }
        }
        gbar();
    }
}

// ---- epilogue FC: out[b][t][o] = sum_h h1[t][b][h]*fc_w[o][h] + fc_b[o] ----
__global__ __launch_bounds__(256) void fc_kern(
    const _Float16* __restrict__ h1a, const _Float16* __restrict__ fcwb,
    const float* __restrict__ fc_b, float* __restrict__ out)
{
    const int wv   = threadIdx.x >> 6;
    const int lane = threadIdx.x & 63;
    const int t    = blockIdx.x * 4 + wv;   // grid 128 -> t = 0..511
    const int kg   = (lane >> 5) << 3;
    const _Float16* ab = h1a + ((size_t)(t + 1) * BATCH + (lane & 31)) * HID + kg;

    #pragma unroll 1
    for (int nt = 0; nt < 8; ++nt) {
        const _Float16* bb = fcwb + (size_t)(nt * 32 + (lane & 31)) * HID + kg;
        f32x16 acc0, acc1;
        #pragma unroll
        for (int r = 0; r < 16; ++r) { acc0[r] = 0.f; acc1[r] = 0.f; }
        #pragma unroll
        for (int kk = 0; kk < 64; kk += 2) {
            half8 a0 = *(const half8*)(ab + kk * 16);
            half8 b0 = *(const half8*)(bb + kk * 16);
            acc0 = __builtin_amdgcn_mfma_f32_32x32x16_f16(a0, b0, acc0, 0, 0, 0);
            half8 a1 = *(const half8*)(ab + (kk + 1) * 16);
            half8 b1 = *(const half8*)(bb + (kk + 1) * 16);
            acc1 = __builtin_amdgcn_mfma_f32_32x32x16_f16(a1, b1, acc1, 0, 0, 0);
        }
        const int o = nt * 32 + (lane & 31);
        const float bias = fc_b[o];
        #pragma unroll
        for (int r = 0; r < 16; ++r) {
            int m = (r & 3) + ((r >> 2) << 3) + ((lane >> 5) << 2);  // batch b
            out[(size_t)m * (T_STEPS * OUT_DIM) + (size_t)t * OUT_DIM + o]
                = acc0[r] + acc1[r] + bias;
        }
    }
}

// ---- pre-cast x (-> [t][b][d] fp16) and fc_w (-> fp16) ----
__global__ __launch_bounds__(256) void precast(
    const float* __restrict__ x, const float* __restrict__ fcw,
    _Float16* __restrict__ xb, _Float16* __restrict__ fcwb)
{
    const int idx = blockIdx.x * 256 + threadIdx.x;
    const int N1 = T_STEPS * BATCH * IN_DIM / 4;  // 1048576
    const int N2 = OUT_DIM * HID / 4;             // 65536
    if (idx < N1) {
        int e = idx << 2;
        int d = e & (IN_DIM - 1);
        int bt = e >> 8;
        int b = bt & 31;
        int t = bt >> 5;
        float4 v = *(const float4*)(x + ((size_t)b * T_STEPS + t) * IN_DIM + d);
        _Float16* dst = xb + e;
        dst[0] = (_Float16)v.x; dst[1] = (_Float16)v.y;
        dst[2] = (_Float16)v.z; dst[3] = (_Float16)v.w;
    } else if (idx < N1 + N2) {
        int e = (idx - N1) << 2;
        float4 v = *(const float4*)(fcw + e);
        _Float16* dst = fcwb + e;
        dst[0] = (_Float16)v.x; dst[1] = (_Float16)v.y;
        dst[2] = (_Float16)v.z; dst[3] = (_Float16)v.w;
    }
}

extern "C" void kernel_launch(void* const* d_in, const int* in_sizes, int n_in,
                              void* d_out, int out_size, void* d_ws, size_t ws_size,
                              hipStream_t stream) {
    const float* x     = (const float*)d_in[0];
    const float* W_ih0 = (const float*)d_in[1];
    const float* W_hh0 = (const float*)d_in[2];
    const float* b_ih0 = (const float*)d_in[3];
    const float* b_hh0 = (const float*)d_in[4];
    const float* W_ih1 = (const float*)d_in[5];
    const float* W_hh1 = (const float*)d_in[6];
    const float* b_ih1 = (const float*)d_in[7];
    const float* b_hh1 = (const float*)d_in[8];
    const float* fc_w  = (const float*)d_in[9];
    const float* fc_b  = (const float*)d_in[10];
    float* out = (float*)d_out;

    char* ws = (char*)d_ws;
    unsigned* flags = (unsigned*)ws;               // 128 flags, 128B apart (16KB)
    unsigned* gen   = (unsigned*)(ws + 16384);     // 8 replicated gen lines (1KB)
    size_t off = 32768;
    _Float16* xb   = (_Float16*)(ws + off); off += (size_t)T_STEPS * BATCH * IN_DIM * 2;
    _Float16* h0a  = (_Float16*)(ws + off); off += (size_t)(T_STEPS + 1) * BATCH * HID * 2;
    _Float16* h1a  = (_Float16*)(ws + off); off += (size_t)(T_STEPS + 1) * BATCH * HID * 2;
    _Float16* fcwb = (_Float16*)(ws + off); off += (size_t)OUT_DIM * HID * 2;
    // total ws use ~76 MB

    hipMemsetAsync(ws, 0, 32768, stream);  // zero barrier state every launch
    precast<<<4352, 256, 0, stream>>>(x, fc_w, xb, fcwb);
    lstm_persist<<<NWG, TPB, 0, stream>>>(W_ih0, W_hh0, b_ih0, b_hh0,
                                          W_ih1, W_hh1, b_ih1, b_hh1,
                                          xb, h0a, h1a, flags, gen);
    fc_kern<<<128, 256, 0, stream>>>(h1a, fcwb, fc_b, out);
}

// Round 3
// 5087.582 us; speedup vs baseline: 3.5212x; 1.0404x over previous
//
#include <hip/hip_runtime.h>
#include <string.h>

// LSTM_13159779795583 : 2-layer LSTM (B=32,T=512,IN=256,H=1024) + FC(1024->256)
//
// Round 3: flat one-level grid barrier with replicated flags.
//  - chain per step: h WT-store ack (syncthreads vmcnt drain) -> flag store
//    propagate -> every WG's wave0 polls all 128 flags -> local release.
//    3 coherent hops vs round-2's 5 (master+gen hops removed).
//  - flags replicated x16 (16 banks x 128 WGs x 128B line each): each polled
//    line has only 8 poller-waves; producers store 16 replicas in parallel
//    from threads 0..15.
//  - all global stores in the persistent kernel remain RELAXED agent-scope
//    atomics (write-through; no L2 maintenance ops anywhere).
//  - everything else (wave roles, MFMA layout, pipelined layers, write-once
//    h slot arrays) as round 2.

#define T_STEPS 512
#define BATCH   32
#define IN_DIM  256
#define HID     1024
#define OUT_DIM 256
#define NWG     128
#define TPB     512
#define UNITS   8     // hidden units per WG per layer
#define ROWS    32    // 4 gates * UNITS
#define NREP    16    // flag replication factor

typedef _Float16 half8  __attribute__((ext_vector_type(8)));
typedef float    f32x16 __attribute__((ext_vector_type(16)));

__device__ __forceinline__ float sigm(float x)      { return 1.f / (1.f + __expf(-x)); }
__device__ __forceinline__ float tanh_fast(float x) { return 2.f / (1.f + __expf(-2.f * x)) - 1.f; }

#define ATOMIC_ST(p, v) __hip_atomic_store((p), (v), __ATOMIC_RELAXED, __HIP_MEMORY_SCOPE_AGENT)
#define ATOMIC_LD(p)    __hip_atomic_load((p), __ATOMIC_RELAXED, __HIP_MEMORY_SCOPE_AGENT)

__global__ __launch_bounds__(TPB, 2) void lstm_persist(
    const float* __restrict__ W_ih0, const float* __restrict__ W_hh0,
    const float* __restrict__ b_ih0, const float* __restrict__ b_hh0,
    const float* __restrict__ W_ih1, const float* __restrict__ W_hh1,
    const float* __restrict__ b_ih1, const float* __restrict__ b_hh1,
    const _Float16* __restrict__ xb,
    _Float16* __restrict__ h0a, _Float16* __restrict__ h1a,
    unsigned* __restrict__ flags)
{
    __shared__ float stage[8][BATCH][33];     // padded vs bank conflicts
    __shared__ float cst[2][BATCH][UNITS];    // cell state, both layers
    __shared__ float biasS[2][ROWS];          // b_ih + b_hh, this WG's rows

    const int tid  = threadIdx.x;
    const int w    = tid >> 6;        // wave id 0..7
    const int lane = tid & 63;
    const int rho  = lane & 31;       // MFMA n-row / A m-row
    const int kg   = (lane >> 5) << 3;// k sub-offset (0 or 8)
    const int blk  = blockIdx.x;

    // wave roles: matrix 0=W_hh0 1=W_ih0 2=W_ih1 3=W_hh1 ; K-range split
    const int matv[8]   = {0, 0,   1, 2, 2,   3, 3,   1};
    const int kbasev[8] = {0, 512, 0, 0, 512, 0, 512, 128};
    const int nkv[8]    = {32, 32, 8, 32, 32, 32, 32, 8};
    const int mat   = matv[w];
    const int kbase = kbasev[w];
    const int nk    = nkv[w];
    const int layer = (mat >= 2) ? 1 : 0;

    const float* wptr; int rowlen;
    if      (mat == 0) { wptr = W_hh0; rowlen = HID;    }
    else if (mat == 1) { wptr = W_ih0; rowlen = IN_DIM; }
    else if (mat == 2) { wptr = W_ih1; rowlen = HID;    }
    else               { wptr = W_hh1; rowlen = HID;    }

    // this lane's weight row: gate = rho>>3, unit = blk*8 + (rho&7)
    const int grow = (rho >> 3) * HID + blk * UNITS + (rho & 7);

    // ---- load + pack B fragments into registers (fp32 -> fp16), once ----
    half8 B[32];
    #pragma unroll
    for (int kk = 0; kk < 32; ++kk) {
        half8 bf;
        if (kk < nk) {
            const float* p = wptr + (size_t)grow * rowlen + kbase + kk * 16 + kg;
            float4 lo = *(const float4*)p;
            float4 hi = *(const float4*)(p + 4);
            bf[0] = (_Float16)lo.x; bf[1] = (_Float16)lo.y;
            bf[2] = (_Float16)lo.z; bf[3] = (_Float16)lo.w;
            bf[4] = (_Float16)hi.x; bf[5] = (_Float16)hi.y;
            bf[6] = (_Float16)hi.z; bf[7] = (_Float16)hi.w;
        } else {
            #pragma unroll
            for (int j = 0; j < 8; ++j) bf[j] = (_Float16)0.f;
        }
        B[kk] = bf;
    }

    // ---- init: biases, cell state, zero h slot 0 (atomic WT stores) ----
    if (tid < ROWS) {
        int gr = (tid >> 3) * HID + blk * UNITS + (tid & 7);
        biasS[0][tid] = b_ih0[gr] + b_hh0[gr];
        biasS[1][tid] = b_ih1[gr] + b_hh1[gr];
    }
    ((float*)cst)[tid] = 0.f;  // 2*32*8 = 512 floats, one per thread
    {
        int i = blk * TPB + tid;
        if (i < BATCH * HID / 2) {
            ATOMIC_ST((unsigned*)h0a + i, 0u);
            ATOMIC_ST((unsigned*)h1a + i, 0u);
        }
    }

    // flag layout: flags[rep*128*32 + wg*32], rep in [0,16), one 128B line per
    // (rep,wg). Pollers of a given line: the 8 WGs with (blk&15)==rep.
    unsigned phase = 0;
    auto gbar = [&]() {
        __syncthreads();   // vmcnt(0) drain: WG's WT stores globally visible
        ++phase;
        if (tid < NREP)
            ATOMIC_ST(&flags[tid * (NWG * 32) + blk * 32], phase);
        if (w == 0) {
            const unsigned* fb = flags + (blk & (NREP - 1)) * (NWG * 32);
            bool d0 = false, d1 = false;
            for (;;) {
                if (!d0) d0 = ATOMIC_LD(&fb[lane * 32])        >= phase;
                if (!d1) d1 = ATOMIC_LD(&fb[(lane + 64) * 32]) >= phase;
                if (__all(d0 && d1)) break;
            }
        }
        __syncthreads();   // release remaining waves
    };

    gbar();  // h slot-0 zeros visible everywhere before step 0

    // ---- pipelined main loop: step s does layer0@t=s and layer1@t=s-1 ----
    for (int s = 0; s <= T_STEPS; ++s) {
        const bool act = (layer == 0) ? (s < T_STEPS) : (s >= 1);
        if (act) {
            const _Float16* ab; int akdim;
            if      (mat == 1) { ab = xb  + (size_t)s * BATCH * IN_DIM;      akdim = IN_DIM; }
            else if (mat == 3) { ab = h1a + (size_t)(s - 1) * BATCH * HID;   akdim = HID;    }
            else               { ab = h0a + (size_t)s * BATCH * HID;         akdim = HID;    }
            const _Float16* ap = ab + (size_t)rho * akdim + kbase + kg;

            f32x16 acc0, acc1;
            #pragma unroll
            for (int r = 0; r < 16; ++r) { acc0[r] = 0.f; acc1[r] = 0.f; }

            #pragma unroll
            for (int kk = 0; kk < 32; kk += 2) {
                if (kk < nk) {
                    half8 a = *(const half8*)(ap + kk * 16);
                    acc0 = __builtin_amdgcn_mfma_f32_32x32x16_f16(a, B[kk], acc0, 0, 0, 0);
                }
                if (kk + 1 < nk) {
                    half8 a = *(const half8*)(ap + (kk + 1) * 16);
                    acc1 = __builtin_amdgcn_mfma_f32_32x32x16_f16(a, B[kk + 1], acc1, 0, 0, 0);
                }
            }
            // C/D layout: n = lane&31, m = (r&3)+8*(r>>2)+4*(lane>>5)
            #pragma unroll
            for (int r = 0; r < 16; ++r) {
                int m = (r & 3) + ((r >> 2) << 3) + ((lane >> 5) << 2);
                stage[w][m][rho] = acc0[r] + acc1[r];
            }
        }
        __syncthreads();

        // ---- cell: 256 threads: (L, b, unit-pair) ----
        if (tid < 256) {
            const int L  = tid >> 7;
            const int r7 = tid & 127;
            const int b  = r7 >> 2;
            const int u0 = (r7 & 3) * 2;
            const bool eact = (L == 0) ? (s < T_STEPS) : (s >= 1);
            if (eact) {
                float hv[2];
                #pragma unroll
                for (int j = 0; j < 2; ++j) {
                    const int u = u0 + j;
                    float pre[4];
                    #pragma unroll
                    for (int g = 0; g < 4; ++g) {
                        int n = g * 8 + u;
                        float v = biasS[L][n];
                        if (L == 0) v += stage[0][b][n] + stage[1][b][n] + stage[2][b][n] + stage[7][b][n];
                        else        v += stage[3][b][n] + stage[4][b][n] + stage[5][b][n] + stage[6][b][n];
                        pre[g] = v;
                    }
                    float iv = sigm(pre[0]);
                    float fv = sigm(pre[1]);
                    float gv = tanh_fast(pre[2]);
                    float ov = sigm(pre[3]);
                    float c  = fv * cst[L][b][u] + iv * gv;
                    cst[L][b][u] = c;
                    hv[j] = ov * tanh_fast(c);
                }
                _Float16 h2[2] = { (_Float16)hv[0], (_Float16)hv[1] };
                unsigned pk;
                memcpy(&pk, h2, 4);
                size_t off32 = ((size_t)b * HID + blk * UNITS + u0) >> 1;
                if (L == 0)
                    ATOMIC_ST((unsigned*)h0a + ((size_t)(s + 1) * BATCH * HID >> 1) + off32, pk);
                else
                    ATOMIC_ST((unsigned*)h1a + ((size_t)s * BATCH * HID >> 1) + off32, pk);
            }
        }
        gbar();
    }
}

// ---- epilogue FC: out[b][t][o] = sum_h h1[t][b][h]*fc_w[o][h] + fc_b[o] ----
__global__ __launch_bounds__(256) void fc_kern(
    const _Float16* __restrict__ h1a, const _Float16* __restrict__ fcwb,
    const float* __restrict__ fc_b, float* __restrict__ out)
{
    const int wv   = threadIdx.x >> 6;
    const int lane = threadIdx.x & 63;
    const int t    = blockIdx.x * 4 + wv;   // grid 128 -> t = 0..511
    const int kg   = (lane >> 5) << 3;
    const _Float16* ab = h1a + ((size_t)(t + 1) * BATCH + (lane & 31)) * HID + kg;

    #pragma unroll 1
    for (int nt = 0; nt < 8; ++nt) {
        const _Float16* bb = fcwb + (size_t)(nt * 32 + (lane & 31)) * HID + kg;
        f32x16 acc0, acc1;
        #pragma unroll
        for (int r = 0; r < 16; ++r) { acc0[r] = 0.f; acc1[r] = 0.f; }
        #pragma unroll
        for (int kk = 0; kk < 64; kk += 2) {
            half8 a0 = *(const half8*)(ab + kk * 16);
            half8 b0 = *(const half8*)(bb + kk * 16);
            acc0 = __builtin_amdgcn_mfma_f32_32x32x16_f16(a0, b0, acc0, 0, 0, 0);
            half8 a1 = *(const half8*)(ab + (kk + 1) * 16);
            half8 b1 = *(const half8*)(bb + (kk + 1) * 16);
            acc1 = __builtin_amdgcn_mfma_f32_32x32x16_f16(a1, b1, acc1, 0, 0, 0);
        }
        const int o = nt * 32 + (lane & 31);
        const float bias = fc_b[o];
        #pragma unroll
        for (int r = 0; r < 16; ++r) {
            int m = (r & 3) + ((r >> 2) << 3) + ((lane >> 5) << 2);  // batch b
            out[(size_t)m * (T_STEPS * OUT_DIM) + (size_t)t * OUT_DIM + o]
                = acc0[r] + acc1[r] + bias;
        }
    }
}

// ---- pre-cast x (-> [t][b][d] fp16) and fc_w (-> fp16) ----
__global__ __launch_bounds__(256) void precast(
    const float* __restrict__ x, const float* __restrict__ fcw,
    _Float16* __restrict__ xb, _Float16* __restrict__ fcwb)
{
    const int idx = blockIdx.x * 256 + threadIdx.x;
    const int N1 = T_STEPS * BATCH * IN_DIM / 4;  // 1048576
    const int N2 = OUT_DIM * HID / 4;             // 65536
    if (idx < N1) {
        int e = idx << 2;
        int d = e & (IN_DIM - 1);
        int bt = e >> 8;
        int b = bt & 31;
        int t = bt >> 5;
        float4 v = *(const float4*)(x + ((size_t)b * T_STEPS + t) * IN_DIM + d);
        _Float16* dst = xb + e;
        dst[0] = (_Float16)v.x; dst[1] = (_Float16)v.y;
        dst[2] = (_Float16)v.z; dst[3] = (_Float16)v.w;
    } else if (idx < N1 + N2) {
        int e = (idx - N1) << 2;
        float4 v = *(const float4*)(fcw + e);
        _Float16* dst = fcwb + e;
        dst[0] = (_Float16)v.x; dst[1] = (_Float16)v.y;
        dst[2] = (_Float16)v.z; dst[3] = (_Float16)v.w;
    }
}

extern "C" void kernel_launch(void* const* d_in, const int* in_sizes, int n_in,
                              void* d_out, int out_size, void* d_ws, size_t ws_size,
                              hipStream_t stream) {
    const float* x     = (const float*)d_in[0];
    const float* W_ih0 = (const float*)d_in[1];
    const float* W_hh0 = (const float*)d_in[2];
    const float* b_ih0 = (const float*)d_in[3];
    const float* b_hh0 = (const float*)d_in[4];
    const float* W_ih1 = (const float*)d_in[5];
    const float* W_hh1 = (const float*)d_in[6];
    const float* b_ih1 = (const float*)d_in[7];
    const float* b_hh1 = (const float*)d_in[8];
    const float* fc_w  = (const float*)d_in[9];
    const float* fc_b  = (const float*)d_in[10];
    float* out = (float*)d_out;

    char* ws = (char*)d_ws;
    unsigned* flags = (unsigned*)ws;     // 16 reps x 128 WGs x 128B = 256KB
    size_t off = 262144;
    _Float16* xb   = (_Float16*)(ws + off); off += (size_t)T_STEPS * BATCH * IN_DIM * 2;
    _Float16* h0a  = (_Float16*)(ws + off); off += (size_t)(T_STEPS + 1) * BATCH * HID * 2;
    _Float16* h1a  = (_Float16*)(ws + off); off += (size_t)(T_STEPS + 1) * BATCH * HID * 2;
    _Float16* fcwb = (_Float16*)(ws + off); off += (size_t)OUT_DIM * HID * 2;
    // total ws use ~76 MB

    hipMemsetAsync(ws, 0, 262144, stream);  // zero flag banks every launch
    precast<<<4352, 256, 0, stream>>>(x, fc_w, xb, fcwb);
    lstm_persist<<<NWG, TPB, 0, stream>>>(W_ih0, W_hh0, b_ih0, b_hh0,
                                          W_ih1, W_hh1, b_ih1, b_hh1,
                                          xb, h0a, h1a, flags);
    fc_kern<<<128, 256, 0, stream>>>(h1a, fcwb, fc_b, out);
}